// Round 1
// 217.899 us; speedup vs baseline: 1.3038x; 1.3038x over previous
//
#include <hip/hip_runtime.h>
#include <math.h>

// PhysQuadModel: batched RK4 rollout of quadrotor dynamics.
// One thread per trajectory (B=8192), 256 sequential RK4 steps.
// R2: quaternion carried as loop state, poly atan2 for output-only log map.
// R3: distance-2 u prefetch. R4/R5: NT stores regressed (write amplification).
// R6: normal float4 stores + depth-8 prefetch. 192us rocprof.
// R7 (this): 128 waves = 1 wave/SIMD -> wall time IS the per-wave serial
//   instruction stream. Attack instruction count:
//   - packed fp32 (v_pk_fma_f32 via ext_vector_type(2)) for component math
//   - Jx==Jy  =>  wdz = tauz/Jz constant across all 4 stages (hoisted)
//   - cz = -2T(qx^2+qy^2); fold 0.5 (quat deriv) and 1/M (acc) into constants
//   - eliminate stage velocities: pos += dt*v + (dt^2/6/M)*(a1+a2+a3)
//   - Newton renorm (c = 1.5 - 0.5*n2) replaces all 4 loop-chain v_rsq;
//     valid since |q|^2 = 1 + O(1e-3) (qdot is orthogonal to q), err ~1e-7.

namespace {
constexpr int   kB    = 8192;
constexpr int   kN    = 256;
constexpr float kDT   = 0.01f;
constexpr float kMG   = 0.033f * 9.81f;        // M*G
constexpr float kTmax = 1.9f * 0.033f * 9.81f; // 0.6150870
constexpr float kKT   = 3.8e-08f;
constexpr float kKC   = 3.8e-11f;
constexpr float kKTA  = kKT * 0.04f;           // KT*ARM
constexpr float kInvM = 1.0f / 0.033f;
constexpr float kJx   = 1.4e-05f, kJz = 2.17e-05f;
constexpr float kInvJx = 1.0f / 1.4e-05f;
constexpr float kInvJz = 1.0f / 2.17e-05f;
constexpr float kA    = (kJz - kJx) * kInvJx;  // 0.55 (Jx==Jy)
constexpr float kTq0  = 0.009f, kTq1 = 0.009f, kTq2 = 0.002f;
constexpr float kH    = 0.005f;                // 0.5*dt          (omega euler)
constexpr float kHq   = 0.0025f;               // 0.5*dt*0.5      (qd' = 2*qd)
constexpr float kDTq  = 0.005f;                // dt*0.5          (stage-4 quat)
constexpr float kDT6  = 0.0016666667f;         // dt/6            (omega comb)
constexpr float kDT6q = 0.5f * kDT6;           // dt/12           (quat comb)
constexpr float kVC   = kDT6 * kInvM;          // dt/6/M  (raw accel -> vel)
constexpr float kPC   = kDT6 * kDT * kInvM;    // dt^2/6/M (raw accel -> pos)
constexpr int   kPF   = 8;                     // prefetch pipeline depth
}

typedef float v2 __attribute__((ext_vector_type(2)));

__device__ __forceinline__ v2 mk2(float a, float b) { v2 r; r.x = a; r.y = b; return r; }

__device__ __forceinline__ float fast_rcp(float x) { return __builtin_amdgcn_rcpf(x); }
__device__ __forceinline__ float fast_rsq(float x) { return __builtin_amdgcn_rsqf(x); }

// atan2 for y >= 0, result in [0, pi]. Minimax atan poly on [0,1], err ~1e-5.
__device__ __forceinline__ float atan2_pos(float y, float x) {
  float axx = fabsf(x);
  float mn  = fminf(y, axx);
  float mx  = fmaxf(y, axx);
  float t   = mn * fast_rcp(mx);
  float t2  = t * t;
  float p = fmaf(t2, -0.01172120f, 0.05265332f);
  p = fmaf(t2, p, -0.11643287f);
  p = fmaf(t2, p, 0.19354346f);
  p = fmaf(t2, p, -0.33262347f);
  p = fmaf(t2, p, 0.99997726f);
  p *= t;
  p = (y > axx) ? (1.5707963268f - p) : p;
  p = (x < 0.0f) ? (3.1415926536f - p) : p;
  return p;
}

// accurate version used ONCE at init (outside the hot loop)
__device__ __forceinline__ void so3_to_quat_init(float rx, float ry, float rz,
                                                 float& qx, float& qy, float& qz, float& qw) {
  float theta = sqrtf(rx * rx + ry * ry + rz * rz);
  float half  = 0.5f * theta;
  float s     = sinf(half);
  float c     = cosf(half);
  float k     = s / (theta + 1e-8f);
  bool  small = theta < 1e-6f;
  k  = small ? 0.5f : k;
  qw = small ? 1.0f : c;
  qx = k * rx; qy = k * ry; qz = k * rz;
}

// log map, output-only path (not fed back into state)
__device__ __forceinline__ void quat_to_so3_fast(float qx, float qy, float qz, float qw,
                                                 float& rx, float& ry, float& rz) {
  float nv2 = qx * qx + qy * qy + qz * qz;
  float nv  = nv2 * fast_rsq(fmaxf(nv2, 1e-20f));   // sqrt(nv2), safe at 0
  float wc  = fminf(fmaxf(qw, -0.999999f), 0.999999f);
  float ang = 2.0f * atan2_pos(nv, wc);
  float k   = ang * fast_rcp(nv + 1e-6f);
  k = (nv < 1e-6f) ? 2.0f : k;
  rx = k * qx; ry = k * qy; rz = k * qz;
}

// One Newton step of rsqrt from y0=1: |q|^2 = 1+eps (eps ~1e-4 per step since
// qdot is orthogonal to q), error 3*eps^2/8 ~ 1e-8. No transcendental.
__device__ __forceinline__ void renorm(v2& a, v2& b) {
  v2 s = a * a + b * b;
  float c = 1.5f - 0.5f * (s.x + s.y);
  a *= c; b *= c;
}

// dyn core, packed. Outputs RAW accel (1/M deferred) and qd' = 2*qd (0.5
// deferred into step constants). wdz is stage-invariant, handled by caller.
__device__ __forceinline__ void dyn_pk(
    v2 q_xy, v2 q_zw, v2 w_xy, float wz,
    float T2, float TmG, v2 s_xy,
    v2& a_xy, float& az, v2& qd_xy, v2& qd_zw, v2& wd_xy) {
  float qx = q_xy.x, qy = q_xy.y, qz = q_zw.x, qw = q_zw.y;
  v2 aq = mk2(qy, -qx);            // aperp(q_xy), shared by thrust + qd
  v2 pw = mk2(-w_xy.y, w_xy.x);    // perp(w_xy), shared by wd + qd
  // thrust_w (raw): t = (2T*qy, -2T*qx, 0); a_raw = qw*t + qz x t
  v2 t_xy = T2 * aq;
  a_xy = qw * t_xy + qz * mk2(-t_xy.y, t_xy.x);
  az   = TmG - T2 * (qx * qx + qy * qy);       // T + cz - MG
  // omega_dot xy: s_xy = tau_xy/Jxy hoisted; kA = (Jz-Jx)/Jx
  wd_xy = s_xy + (kA * wz) * pw;
  // qd' = 2 * quat_derivative
  qd_xy = qw * w_xy + wz * aq + qz * pw;
  qd_zw = wz * mk2(qw, -qz) + qx * mk2(w_xy.y, -w_xy.x) - qy * w_xy;
}

__global__ __launch_bounds__(64) void quad_rk4_kernel(
    const float* __restrict__ x0,
    const float* __restrict__ u_seq,
    float* __restrict__ out) {
  const int b = blockIdx.x * 64 + threadIdx.x;
  if (b >= kB) return;

  const float4* xv = reinterpret_cast<const float4*>(x0) + (size_t)b * 3;
  float4 s0 = xv[0], s1 = xv[1], s2 = xv[2];
  v2    p_xy = mk2(s0.x, s0.y);  float pz = s0.z;
  v2    v_xy = mk2(s0.w, s1.x);  float vz = s1.y;
  v2    o_xy = mk2(s2.y, s2.z);  float oz = s2.w;

  float qx0, qy0, qz0, qw0;
  so3_to_quat_init(s1.z, s1.w, s2.x, qx0, qy0, qz0, qw0);
  v2 q_xy = mk2(qx0, qy0), q_zw = mk2(qz0, qw0);   // loop-carried unit quat

  const float4* uv = reinterpret_cast<const float4*>(u_seq) + (size_t)b * kN;
  float4*       ov = reinterpret_cast<float4*>(out) + (size_t)b * kN * 3;

  // depth-8 software-prefetch pipeline
  float4 u0 = uv[0], u1 = uv[1], u2 = uv[2], u3 = uv[3],
         u4 = uv[4], u5 = uv[5], u6 = uv[6], u7 = uv[7];

#pragma unroll 8
  for (int t = 0; t < kN; ++t) {
    float4 u_new = uv[(t + kPF < kN) ? (t + kPF) : (kN - 1)];
    float4 u = u0;

    // ---- motor_to_phys + per-step invariants ----
    v2 ua = mk2(u.x, u.y), ub = mk2(u.z, u.w);
    v2 w2a = ua * ua, w2b = ub * ub;
    float sa = w2a.x + w2a.y, sb = w2b.x + w2b.y;
    float T   = fminf(kKT * (sa + sb), kTmax);           // >= 0 always
    float tq1 = kKTA * (sb - sa);
    float tq2 = kKTA * ((w2a.y + w2b.x) - (w2a.x + w2b.y));
    float tq3 = kKC  * ((w2a.x + w2b.x) - (w2a.y + w2b.y));
    tq1 = fminf(fmaxf(tq1, -kTq0), kTq0);
    tq2 = fminf(fmaxf(tq2, -kTq1), kTq1);
    tq3 = fminf(fmaxf(tq3, -kTq2), kTq2);
    v2    s_xy = mk2(tq1 * kInvJx, tq2 * kInvJx);
    float wdz  = tq3 * kInvJz;        // stage-invariant (Jx==Jy)
    float T2   = T + T, TmG = T - kMG;
    float ozh  = oz + kH  * wdz;      // omega_z at stages 2,3
    float ozf  = oz + kDT * wdz;      // omega_z at stage 4 AND new omega_z

    // ---- stage 1 ----
    v2 a1, qd1_xy, qd1_zw, wd1; float az1;
    dyn_pk(q_xy, q_zw, o_xy, oz, T2, TmG, s_xy, a1, az1, qd1_xy, qd1_zw, wd1);

    // ---- stage 2 ----
    v2 q2_xy = q_xy + kHq * qd1_xy, q2_zw = q_zw + kHq * qd1_zw;
    renorm(q2_xy, q2_zw);
    v2 o2 = o_xy + kH * wd1;
    v2 a2, qd2_xy, qd2_zw, wd2; float az2;
    dyn_pk(q2_xy, q2_zw, o2, ozh, T2, TmG, s_xy, a2, az2, qd2_xy, qd2_zw, wd2);

    // ---- stage 3 ----
    v2 q3_xy = q_xy + kHq * qd2_xy, q3_zw = q_zw + kHq * qd2_zw;
    renorm(q3_xy, q3_zw);
    v2 o3 = o_xy + kH * wd2;
    v2 a3, qd3_xy, qd3_zw, wd3; float az3;
    dyn_pk(q3_xy, q3_zw, o3, ozh, T2, TmG, s_xy, a3, az3, qd3_xy, qd3_zw, wd3);

    // ---- stage 4 (full step) ----
    v2 q4_xy = q_xy + kDTq * qd3_xy, q4_zw = q_zw + kDTq * qd3_zw;
    renorm(q4_xy, q4_zw);
    v2 o4 = o_xy + kDT * wd3;
    v2 a4, qd4_xy, qd4_zw, wd4; float az4;
    dyn_pk(q4_xy, q4_zw, o4, ozf, T2, TmG, s_xy, a4, az4, qd4_xy, qd4_zw, wd4);

    // ---- RK4 combine ----
    // pos_n = pos + dt*v + (dt^2/6/M)*(a1r+a2r+a3r)   (stage vels eliminated)
    v2 t23 = a2 + a3;
    v2 Apos = a1 + t23;
    v2 Avel = Apos + t23 + a4;        // a1 + 2a2 + 2a3 + a4
    p_xy = p_xy + kDT * v_xy;  p_xy = p_xy + kPC * Apos;
    float az23 = az2 + az3;
    float Aposz = az1 + az23;
    float Avelz = Aposz + az23 + az4;
    pz = fmaf(kDT, vz, pz);  pz = fmaf(kPC, Aposz, pz);
    v_xy = v_xy + kVC * Avel;
    vz   = fmaf(kVC, Avelz, vz);
    v2 w23 = wd2 + wd3;
    o_xy = o_xy + kDT6 * ((wd1 + w23) + (w23 + wd4));
    oz = ozf;
    v2 qxy23 = qd2_xy + qd3_xy;
    q_xy = q_xy + kDT6q * ((qd1_xy + qxy23) + (qxy23 + qd4_xy));
    v2 qzw23 = qd2_zw + qd3_zw;
    q_zw = q_zw + kDT6q * ((qd1_zw + qzw23) + (qzw23 + qd4_zw));
    renorm(q_xy, q_zw);

    // ---- output so3 (off the loop-carried chain) + store ----
    float rx, ry, rz;
    quat_to_so3_fast(q_xy.x, q_xy.y, q_zw.x, q_zw.y, rx, ry, rz);
    ov[t * 3 + 0] = make_float4(p_xy.x, p_xy.y, pz, v_xy.x);
    ov[t * 3 + 1] = make_float4(v_xy.y, vz, rx, ry);
    ov[t * 3 + 2] = make_float4(rz, o_xy.x, o_xy.y, oz);

    // rotate the 8-deep prefetch pipeline
    u0 = u1; u1 = u2; u2 = u3; u3 = u4; u4 = u5; u5 = u6; u6 = u7; u7 = u_new;
  }
}

extern "C" void kernel_launch(void* const* d_in, const int* in_sizes, int n_in,
                              void* d_out, int out_size, void* d_ws, size_t ws_size,
                              hipStream_t stream) {
  const float* x0    = (const float*)d_in[0];   // (8192, 12)
  const float* u_seq = (const float*)d_in[1];   // (8192, 256, 4)
  float*       out   = (float*)d_out;           // (8192, 256, 12)
  (void)in_sizes; (void)n_in; (void)out_size; (void)d_ws; (void)ws_size;

  dim3 block(64);
  dim3 grid(kB / 64);   // 128 waves, 1 thread per trajectory, 1 wave/SIMD
  quad_rk4_kernel<<<grid, block, 0, stream>>>(x0, u_seq, out);
}